// Round 7
// baseline (627.642 us; speedup 1.0000x reference)
//
#include <hip/hip_runtime.h>
#include <hip/hip_bf16.h>
#include <stdint.h>

// Problem dims (fixed by reference): B=64, T=512, H=1024, A=300
#define B_DIM 64
#define T_DIM 512
#define H_DIM 1024
#define K_DIM 1024
#define M_DIM (B_DIM * T_DIM)

typedef int i32x4 __attribute__((ext_vector_type(4)));
typedef int i32x8 __attribute__((ext_vector_type(8)));
typedef float f32x2 __attribute__((ext_vector_type(2)));
typedef float f32x16 __attribute__((ext_vector_type(16)));

__device__ __forceinline__ float tanh_fast(float x) {
  float e = __expf(2.0f * x);
  return 1.0f - 2.0f / (e + 1.0f);
}

// async global->LDS, 16B per lane. LDS dest must be wave-uniform base + lane*16.
__device__ __forceinline__ void async_cp16(const void* gp, void* lp) {
  __builtin_amdgcn_global_load_lds(
      reinterpret_cast<const __attribute__((address_space(1))) uint32_t*>(
          reinterpret_cast<uintptr_t>(gp)),
      reinterpret_cast<__attribute__((address_space(3))) uint32_t*>(
          reinterpret_cast<uintptr_t>(lp)),
      16, 0, 0);
}

// ---------- cvt hidden fp32 -> fp8 e4m3, scaled x16 (std 1.0 -> 16) ----------
__global__ void cvt_hidden_kernel(const float* __restrict__ src, int* __restrict__ dst) {
  int i = blockIdx.x * 256 + threadIdx.x;  // one dword = 4 fp8
  float4 v = reinterpret_cast<const float4*>(src)[i];
  int d = __builtin_amdgcn_cvt_pk_fp8_f32(v.x * 16.f, v.y * 16.f, 0, false);
  d = __builtin_amdgcn_cvt_pk_fp8_f32(v.z * 16.f, v.w * 16.f, d, true);
  dst[i] = d;
}

// ---- cvt W_h (x32) -> fp8 (1024 blocks) + zero scores (32) + zero r (64) ----
__global__ void cvtW_zero_kernel(const float* __restrict__ Wh, int* __restrict__ whF8,
                                 float* __restrict__ scores, float* __restrict__ r) {
  int bid = blockIdx.x, tid = threadIdx.x;
  if (bid < 1024) {
    int i = bid * 256 + tid;
    float4 v = reinterpret_cast<const float4*>(Wh)[i];
    int d = __builtin_amdgcn_cvt_pk_fp8_f32(v.x * 32.f, v.y * 32.f, 0, false);
    d = __builtin_amdgcn_cvt_pk_fp8_f32(v.z * 32.f, v.w * 32.f, d, true);
    whF8[i] = d;
  } else if (bid < 1056) {
    int i = (bid - 1024) * 256 + tid;   // scores: 32768 floats = 8192 float4
    reinterpret_cast<float4*>(scores)[i] = make_float4(0.f, 0.f, 0.f, 0.f);
  } else {
    int i = (bid - 1056) * 256 + tid;   // r: 65536 floats = 16384 float4 (64 blocks)
    reinterpret_cast<float4*>(r)[i] = make_float4(0.f, 0.f, 0.f, 0.f);
  }
}

// ---------------- fused fp8-MX GEMM + tanh + dot(w_w) -> scores ----------------
// A = hidden*16 (fp8), B = W_h*32 (fp8); scales 2^-4 / 2^-5 folded into the MFMA
// scale operands (e8m0 123/122) so acc = hidden.W_h exactly. Block 256Mx128N,
// 4 waves each 128x64 via 32x32x64 tiles (4m x 2n, acc 8x16 f32 = 128 AGPR).
// LDS 16KB A + 8KB B in 16B chunks, c = kc*256+row (A) / kc*128+row (B).
// Frag layout (generalized from m89-verified bf16): A[m=lane&31][k=(lane>>5)*32+byte],
// C/D 32x32 (m74/m101-verified): col=lane&31, row=(reg&3)+8*(reg>>2)+4*(lane>>5).
// XCD swizzle m=bid&127, n=bid>>7 (R4/R6-verified FETCH cut).
#define GM_BK 64
__global__ __launch_bounds__(256, 2) void gemm_scores_kernel(
    const uint8_t* __restrict__ Af8, const uint8_t* __restrict__ Bf8,
    const float* __restrict__ bh, const float* __restrict__ ww,
    float* __restrict__ scores) {
  __shared__ __attribute__((aligned(16))) uint8_t lA[256 * GM_BK];  // 16 KB
  __shared__ __attribute__((aligned(16))) uint8_t lB[128 * GM_BK];  // 8 KB

  const int tid = threadIdx.x;
  const int bid = blockIdx.x;
  const int m0 = (bid & 127) * 256;
  const int n0 = (bid >> 7) * 128;

  const int wv = tid >> 6;
  const int lane = tid & 63;
  const int wm = wv & 1, wn = wv >> 1;   // waves 2m x 2n, each 128x64
  const int r32 = lane & 31, khalf = lane >> 5;

  f32x16 acc[4][2] = {};

  // staging: A 4 chunks/thread (c = kc*256 + row, kc=j, row=tid),
  //          B 2 chunks/thread (c = kc*128 + row)
  const uint8_t* gA[4]; uint8_t* lAd[4];
#pragma unroll
  for (int j = 0; j < 4; ++j) {
    gA[j] = Af8 + (size_t)(m0 + tid) * K_DIM + j * 16;
    lAd[j] = &lA[(j * 256 + tid) * 16];
  }
  const uint8_t* gB[2]; uint8_t* lBd[2];
#pragma unroll
  for (int j = 0; j < 2; ++j) {
    int c = j * 256 + tid;
    int row = c & 127, kc = c >> 7;
    gB[j] = Bf8 + (size_t)(n0 + row) * K_DIM + kc * 16;
    lBd[j] = &lB[c * 16];
  }

  // fragment LDS base offsets (h=0 chunk; h=1 chunk at +256*16 (A) / +128*16 (B))
  const uint8_t* paf[4];
#pragma unroll
  for (int mi = 0; mi < 4; ++mi)
    paf[mi] = &lA[((khalf * 2) * 256 + wm * 128 + mi * 32 + r32) * 16];
  const uint8_t* pbf[2];
#pragma unroll
  for (int ni = 0; ni < 2; ++ni)
    pbf[ni] = &lB[((khalf * 2) * 128 + wn * 64 + ni * 32 + r32) * 16];

#pragma unroll
  for (int k0 = 0; k0 < K_DIM; k0 += GM_BK) {
#pragma unroll
    for (int j = 0; j < 4; ++j) async_cp16(gA[j] + k0, lAd[j]);
#pragma unroll
    for (int j = 0; j < 2; ++j) async_cp16(gB[j] + k0, lBd[j]);
    __syncthreads();

    i32x8 bfr[2];
#pragma unroll
    for (int ni = 0; ni < 2; ++ni) {
      i32x4 lo = *reinterpret_cast<const i32x4*>(pbf[ni]);
      i32x4 hi = *reinterpret_cast<const i32x4*>(pbf[ni] + 128 * 16);
      bfr[ni] = __builtin_shufflevector(lo, hi, 0, 1, 2, 3, 4, 5, 6, 7);
    }
    i32x8 af[4];
#pragma unroll
    for (int mi = 0; mi < 4; ++mi) {
      i32x4 lo = *reinterpret_cast<const i32x4*>(paf[mi]);
      i32x4 hi = *reinterpret_cast<const i32x4*>(paf[mi] + 256 * 16);
      af[mi] = __builtin_shufflevector(lo, hi, 0, 1, 2, 3, 4, 5, 6, 7);
    }
#pragma unroll
    for (int mi = 0; mi < 4; ++mi)
#pragma unroll
      for (int ni = 0; ni < 2; ++ni)
        acc[mi][ni] = __builtin_amdgcn_mfma_scale_f32_32x32x64_f8f6f4(
            af[mi], bfr[ni], acc[mi][ni], 0, 0,
            0, 0x7B7B7B7B,   // A scale: e8m0 123 = 2^-4 (replicated all bytes)
            0, 0x7A7A7A7A);  // B scale: e8m0 122 = 2^-5
    __syncthreads();
  }

  // epilogue: C/D 32x32 layout col=lane&31, row=(reg&3)+8*(reg>>2)+4*khalf
  float bhv[2], wwv[2];
#pragma unroll
  for (int ni = 0; ni < 2; ++ni) {
    int n = n0 + wn * 64 + ni * 32 + r32;
    bhv[ni] = bh[n];
    wwv[ni] = ww[n];
  }
#pragma unroll
  for (int mi = 0; mi < 4; ++mi) {
#pragma unroll
    for (int rg = 0; rg < 16; ++rg) {
      float s = tanh_fast(acc[mi][0][rg] + bhv[0]) * wwv[0] +
                tanh_fast(acc[mi][1][rg] + bhv[1]) * wwv[1];
      s += __shfl_xor(s, 1, 32);
      s += __shfl_xor(s, 2, 32);
      s += __shfl_xor(s, 4, 32);
      s += __shfl_xor(s, 8, 32);
      s += __shfl_xor(s, 16, 32);
      if (r32 == 0) {
        int m = m0 + wm * 128 + mi * 32 + (rg & 3) + 8 * (rg >> 2) + 4 * khalf;
        atomicAdd(&scores[m], s);
      }
    }
  }
}

// ------- fused softmax (recomputed per block) + weighted sum r (512 blocks) -------
// reads fp8 hidden copy (x16 scale folded out at the end)
__global__ void wsum_kernel(const float* __restrict__ scores,
                            const uint8_t* __restrict__ hidF8,
                            float* __restrict__ r) {
  __shared__ float al[64];
  __shared__ float red[8];
  const int bid = blockIdx.x, tid = threadIdx.x;
  const int b = bid >> 3, tc = bid & 7;
  const int wv = tid >> 6, lane = tid & 63;
  float v0 = scores[b * T_DIM + tid];
  float v1 = scores[b * T_DIM + 256 + tid];
  float mx = fmaxf(v0, v1);
#pragma unroll
  for (int off = 1; off < 64; off <<= 1) mx = fmaxf(mx, __shfl_xor(mx, off, 64));
  if (lane == 0) red[wv] = mx;
  __syncthreads();
  mx = fmaxf(fmaxf(red[0], red[1]), fmaxf(red[2], red[3]));
  float e0 = __expf(v0 - mx), e1 = __expf(v1 - mx);
  float s = e0 + e1;
#pragma unroll
  for (int off = 1; off < 64; off <<= 1) s += __shfl_xor(s, off, 64);
  if (lane == 0) red[4 + wv] = s;
  __syncthreads();
  float inv = 1.0f / (red[4] + red[5] + red[6] + red[7]);
  if (tid < 64) al[tid] = __expf(scores[b * T_DIM + tc * 64 + tid] - mx) * inv;
  __syncthreads();
  const int* hp = reinterpret_cast<const int*>(hidF8) +
                  ((size_t)b * T_DIM * H_DIM + (size_t)tc * 64 * H_DIM) / 4 + tid;
  float4 acc = make_float4(0.f, 0.f, 0.f, 0.f);
#pragma unroll 8
  for (int t = 0; t < 64; ++t) {
    float a = al[t];
    int u = hp[t * (H_DIM / 4)];
    f32x2 lo = __builtin_amdgcn_cvt_pk_f32_fp8(u, false);
    f32x2 hi = __builtin_amdgcn_cvt_pk_f32_fp8(u, true);
    acc.x += a * lo[0];
    acc.y += a * lo[1];
    acc.z += a * hi[0];
    acc.w += a * hi[1];
  }
  float* rp = r + b * H_DIM + tid * 4;
  atomicAdd(rp + 0, acc.x * 0.0625f);
  atomicAdd(rp + 1, acc.y * 0.0625f);
  atomicAdd(rp + 2, acc.z * 0.0625f);
  atomicAdd(rp + 3, acc.w * 0.0625f);
}

// ---------------- dst[i,h] = bias[h] + src_row_i . W[h,:] ----------------
// grid (H/64, B) = 1024 blocks; 4 lanes split K per output h; shfl-reduce.
__global__ void rowvec_matT_kernel(const float* __restrict__ src, size_t src_stride,
                                   const float* __restrict__ W, const float* __restrict__ bias,
                                   float* __restrict__ dst) {
  __shared__ float sv[H_DIM];
  const int i = blockIdx.y, h0 = blockIdx.x * 64, tid = threadIdx.x;
  reinterpret_cast<float4*>(sv)[tid] =
      reinterpret_cast<const float4*>(src + (size_t)i * src_stride)[tid];
  __syncthreads();
  const int hl = tid >> 2;
  const int kq = tid & 3;
  const float* wr = W + (size_t)(h0 + hl) * H_DIM + kq * 256;
  const float* svp = sv + kq * 256;
  float acc = 0.f;
#pragma unroll 4
  for (int k = 0; k < 256; k += 4) {
    float4 w4 = *reinterpret_cast<const float4*>(wr + k);
    float4 s4 = *reinterpret_cast<const float4*>(svp + k);
    acc += w4.x * s4.x + w4.y * s4.y + w4.z * s4.z + w4.w * s4.w;
  }
  acc += __shfl_xor(acc, 1, 4);
  acc += __shfl_xor(acc, 2, 4);
  if (kq == 0) dst[(size_t)i * H_DIM + h0 + hl] = acc + bias[h0 + hl];
}

// ---------------- out[i,j,h] = tanh(rp[i,h] + xq[j,h])  [B,B,H] quirk ----------------
__global__ void final_kernel(const float* __restrict__ rp, const float* __restrict__ xq,
                             float* __restrict__ out) {
  int idx = blockIdx.x * 256 + threadIdx.x;
  int e = idx * 4;
  int i = e >> 16;
  int j = (e >> 10) & 63;
  int h = e & 1023;
  float4 a = *reinterpret_cast<const float4*>(&rp[i * H_DIM + h]);
  float4 b = *reinterpret_cast<const float4*>(&xq[j * H_DIM + h]);
  float4 o;
  o.x = tanh_fast(a.x + b.x);
  o.y = tanh_fast(a.y + b.y);
  o.z = tanh_fast(a.z + b.z);
  o.w = tanh_fast(a.w + b.w);
  *reinterpret_cast<float4*>(&out[e]) = o;
}

extern "C" void kernel_launch(void* const* d_in, const int* in_sizes, int n_in,
                              void* d_out, int out_size, void* d_ws, size_t ws_size,
                              hipStream_t stream) {
  const float* hidden = (const float*)d_in[0];
  // aspect (1), W_v (4), b_v (5), w_b (7) cancel under softmax -> unused
  const float* W_h = (const float*)d_in[2];
  const float* b_h = (const float*)d_in[3];
  const float* w_w = (const float*)d_in[6];  // use first H entries
  const float* W_p = (const float*)d_in[8];
  const float* b_p = (const float*)d_in[9];
  const float* W_x = (const float*)d_in[10];
  const float* b_x = (const float*)d_in[11];
  float* out = (float*)d_out;

  char* ws = (char*)d_ws;
  uint8_t* hidF8 = (uint8_t*)ws;                 // 32 MB
  uint8_t* whF8 = (uint8_t*)(ws + 33554432);     // 1 MB
  float* scores = (float*)(ws + 34603008);       // 128 KB
  float* r = (float*)(ws + 34734080);            // 256 KB
  float* rp = (float*)(ws + 34996224);           // 256 KB
  float* xq = (float*)(ws + 35258368);           // 256 KB

  // 1) cvt hidden (x16) -> fp8; cvt W_h (x32) -> fp8 + zero scores/r
  cvt_hidden_kernel<<<32768, 256, 0, stream>>>(hidden, (int*)hidF8);
  cvtW_zero_kernel<<<1120, 256, 0, stream>>>(W_h, (int*)whF8, scores, r);

  // 2) fused fp8-MX GEMM -> scores (256x128 tiles, 1024 blocks, XCD-swizzled)
  gemm_scores_kernel<<<1024, 256, 0, stream>>>(hidF8, whF8, b_h, w_w, scores);

  // 3) softmax + weighted sum (fused, 512 blocks)
  wsum_kernel<<<512, 256, 0, stream>>>(scores, hidF8, r);

  // 4) rp = r @ W_p^T + b_p ; xq = hidden[:,-1,:] @ W_x^T + b_x
  rowvec_matT_kernel<<<dim3(H_DIM / 64, B_DIM), 256, 0, stream>>>(r, (size_t)H_DIM, W_p, b_p, rp);
  rowvec_matT_kernel<<<dim3(H_DIM / 64, B_DIM), 256, 0, stream>>>(
      hidden + (size_t)(T_DIM - 1) * H_DIM, (size_t)T_DIM * H_DIM, W_x, b_x, xq);

  // 5) out[i,j,h] = tanh(rp[i,h] + xq[j,h])
  final_kernel<<<(B_DIM * B_DIM * H_DIM / 4) / 256, 256, 0, stream>>>(rp, xq, out);
}